// Round 6
// baseline (39411.047 us; speedup 1.0000x reference)
//
#include <hip/hip_runtime.h>
#include <stdint.h>
#include <stddef.h>

// LSTMNetwork: 3-layer stacked LSTM, batch=1, T=4096, IN=64, H=1024, OUT=1.
// ALL inputs are FLOAT32 (reference is jnp.float32; rounds 1-5 forensic:
// reading fp32 words as bf16 halves produced deterministic NaN, whose bf16
// 2-byte store read back as an fp32 denormal ~= 0 -- reproducing the empty
// stub absmax bit-exactly for 4 rounds). Output fp32.
//
// Design: one wave per hidden unit (1024 waves = 256 blocks x 256 thr,
// __launch_bounds__(256,1) => 1 block/CU => all 256 blocks co-resident).
// Recurrent + input weights live in VGPRs (fp32, 128 regs/lane). h exchange
// via 64-bit tagged slots [tag32|fp32] with relaxed agent-scope atomics in
// __device__ .bss buffers. Plain launches only; tag hygiene via zero kernel.

#define T_STEPS 4096
#define HD      1024
#define NWG     256
#define NTHR    256
#define RINGR   16

typedef unsigned long long u64;

// ~64.1 MB module .bss -- harness never pokes these.
__device__ u64 g_bufA[(size_t)T_STEPS * HD];  // layer0 out / layer1 in (32 MB)
__device__ u64 g_bufB[(size_t)T_STEPS * HD];  // layer1 out / layer2 in (32 MB)
__device__ u64 g_ring[RINGR * HD];            // layer2 intra-layer ring (128 KB)

__global__ __launch_bounds__(256)
void zero_bufs()
{
    const size_t gtid = (size_t)blockIdx.x * blockDim.x + threadIdx.x;
    const size_t step = (size_t)gridDim.x * blockDim.x;
    for (size_t i = gtid; i < (size_t)T_STEPS * HD; i += step) g_bufA[i] = 0ULL;
    for (size_t i = gtid; i < (size_t)T_STEPS * HD; i += step) g_bufB[i] = 0ULL;
    for (size_t i = gtid; i < (size_t)RINGR * HD;  i += step) g_ring[i] = 0ULL;
}

// LAYER 0: x from seq (fp32 [T][64]).  LAYER 1/2: x from prev layer's slot
// buffer (plain loads -- prior kernel completed, stream-ordered).
template <int LAYER>
__global__ __launch_bounds__(NTHR, 1)
void scan_kernel(const float* __restrict__ seq,
                 const float* __restrict__ w_ih,
                 const float* __restrict__ w_hh,
                 const float* __restrict__ b_ih,
                 const float* __restrict__ b_hh)
{
    u64*           hbuf    = (LAYER == 0) ? g_bufA : (LAYER == 1) ? g_bufB : g_ring;
    const u64*     xin     = (LAYER == 1) ? g_bufA : g_bufB;   // unused for LAYER 0
    const uint32_t tagbase = (LAYER == 0) ? 0x1000u : (LAYER == 1) ? 0x3000u : 0x5000u;
    const uint32_t rmask   = (LAYER == 2) ? (RINGR - 1) : 0xFFFFFFFFu;

    const int lane = threadIdx.x & 63;
    const int wave = threadIdx.x >> 6;
    const int j    = blockIdx.x * 4 + wave;      // hidden unit owned by this wave

    const int r0 = 0 * HD + j;   // i gate row
    const int r1 = 1 * HD + j;   // f
    const int r2 = 2 * HD + j;   // g
    const int r3 = 3 * HD + j;   // o

    // ---- recurrent weights into registers (fp32) ----
    float whh0[16], whh1[16], whh2[16], whh3[16];
    {
        const float* p0 = w_hh + (size_t)r0 * HD;
        const float* p1 = w_hh + (size_t)r1 * HD;
        const float* p2 = w_hh + (size_t)r2 * HD;
        const float* p3 = w_hh + (size_t)r3 * HD;
#pragma unroll
        for (int i = 0; i < 16; ++i) {
            whh0[i] = p0[64 * i + lane];
            whh1[i] = p1[64 * i + lane];
            whh2[i] = p2[64 * i + lane];
            whh3[i] = p3[64 * i + lane];
        }
    }

    float wih0[16], wih1[16], wih2[16], wih3[16];             // LAYER 1/2 (K=1024)
    float wi0v0 = 0.f, wi0v1 = 0.f, wi0v2 = 0.f, wi0v3 = 0.f; // LAYER 0   (K=64)
    if (LAYER != 0) {
        const float* p0 = w_ih + (size_t)r0 * HD;
        const float* p1 = w_ih + (size_t)r1 * HD;
        const float* p2 = w_ih + (size_t)r2 * HD;
        const float* p3 = w_ih + (size_t)r3 * HD;
#pragma unroll
        for (int i = 0; i < 16; ++i) {
            wih0[i] = p0[64 * i + lane];
            wih1[i] = p1[64 * i + lane];
            wih2[i] = p2[64 * i + lane];
            wih3[i] = p3[64 * i + lane];
        }
    } else {
        wi0v0 = w_ih[(size_t)r0 * 64 + lane];
        wi0v1 = w_ih[(size_t)r1 * 64 + lane];
        wi0v2 = w_ih[(size_t)r2 * 64 + lane];
        wi0v3 = w_ih[(size_t)r3 * 64 + lane];
    }

    const float bias0 = b_ih[r0] + b_hh[r0];
    const float bias1 = b_ih[r1] + b_hh[r1];
    const float bias2 = b_ih[r2] + b_hh[r2];
    const float bias3 = b_ih[r3] + b_hh[r3];

    float c = 0.0f;   // cell state (lane 0 of each wave)

    for (int t = 0; t < T_STEPS; ++t) {
        // ---- x contribution (data ready; issues ahead of the poll) ----
        float xa0, xa1, xa2, xa3;
        if (LAYER == 0) {
            const float xv = seq[(size_t)t * 64 + lane];
            xa0 = wi0v0 * xv; xa1 = wi0v1 * xv; xa2 = wi0v2 * xv; xa3 = wi0v3 * xv;
        } else {
            xa0 = xa1 = xa2 = xa3 = 0.f;
            const u64* xrow = xin + (size_t)t * HD;
#pragma unroll
            for (int i = 0; i < 16; ++i) {
                const float xv = __uint_as_float((uint32_t)xrow[64 * i + lane]);
                xa0 = __fmaf_rn(wih0[i], xv, xa0);
                xa1 = __fmaf_rn(wih1[i], xv, xa1);
                xa2 = __fmaf_rn(wih2[i], xv, xa2);
                xa3 = __fmaf_rn(wih3[i], xv, xa3);
            }
        }

        // ---- recurrent: poll 64-bit tagged slots of h[t-1] ----
        float acc0, acc1, acc2, acc3;
        if (t == 0) {
            acc0 = xa0; acc1 = xa1; acc2 = xa2; acc3 = xa3;   // h[-1] = 0
        } else {
            const uint32_t tag  = tagbase + (uint32_t)(t - 1);
            const u64*     hrow = hbuf + (size_t)((uint32_t)(t - 1) & rmask) * HD;
            for (;;) {
                uint32_t bad = 0;
                float a0 = xa0, a1 = xa1, a2 = xa2, a3 = xa3;
#pragma unroll
                for (int i = 0; i < 16; ++i) {
                    const u64 u = __hip_atomic_load(hrow + 64 * i + lane,
                                                    __ATOMIC_RELAXED,
                                                    __HIP_MEMORY_SCOPE_AGENT);
                    bad |= (uint32_t)(u >> 32) ^ tag;
                    const float hv = __uint_as_float((uint32_t)u);
                    a0 = __fmaf_rn(whh0[i], hv, a0);
                    a1 = __fmaf_rn(whh1[i], hv, a1);
                    a2 = __fmaf_rn(whh2[i], hv, a2);
                    a3 = __fmaf_rn(whh3[i], hv, a3);
                }
                if (bad == 0) { acc0 = a0; acc1 = a1; acc2 = a2; acc3 = a3; break; }
            }
        }

        // ---- reduce 4 gate dot-products across 64 lanes ----
#pragma unroll
        for (int m = 1; m < 64; m <<= 1) {
            acc0 += __shfl_xor(acc0, m, 64);
            acc1 += __shfl_xor(acc1, m, 64);
            acc2 += __shfl_xor(acc2, m, 64);
            acc3 += __shfl_xor(acc3, m, 64);
        }

        // ---- lane-0 epilogue: activations, state, publish ----
        if (lane == 0) {
            const float ig = 1.0f / (1.0f + expf(-(acc0 + bias0)));
            const float fg = 1.0f / (1.0f + expf(-(acc1 + bias1)));
            const float gg = tanhf(acc2 + bias2);
            const float og = 1.0f / (1.0f + expf(-(acc3 + bias3)));
            c = fg * c + ig * gg;
            const float h = og * tanhf(c);
            const u64 slot = ((u64)(tagbase + (uint32_t)t) << 32)
                           | (u64)__float_as_uint(h);
            __hip_atomic_store(hbuf + (size_t)((uint32_t)t & rmask) * HD + j, slot,
                               __ATOMIC_RELAXED, __HIP_MEMORY_SCOPE_AGENT);
        }
    }
}

__global__ __launch_bounds__(256)
void final_kernel(const float* __restrict__ w_lin,
                  const float* __restrict__ b_lin,
                  float*       __restrict__ out)
{
    __shared__ float red[256];
    const int tid = threadIdx.x;
    const u64* hrow = g_ring + (size_t)((T_STEPS - 1) & (RINGR - 1)) * HD;
    float s = 0.f;
#pragma unroll
    for (int i = 0; i < 4; ++i) {
        const int k = tid + 256 * i;
        s += __uint_as_float((uint32_t)hrow[k]) * w_lin[k];
    }
    red[tid] = s;
    __syncthreads();
    for (int o = 128; o > 0; o >>= 1) {
        if (tid < o) red[tid] += red[tid + o];
        __syncthreads();
    }
    if (tid == 0) out[0] = red[0] + b_lin[0];
}

extern "C" void kernel_launch(void* const* d_in, const int* in_sizes, int n_in,
                              void* d_out, int out_size, void* d_ws, size_t ws_size,
                              hipStream_t stream)
{
    (void)in_sizes; (void)n_in; (void)out_size; (void)d_ws; (void)ws_size;

    const float* seq   = (const float*)d_in[0];
    const float* w_ih0 = (const float*)d_in[1];
    const float* w_hh0 = (const float*)d_in[2];
    const float* b_ih0 = (const float*)d_in[3];
    const float* b_hh0 = (const float*)d_in[4];
    const float* w_ih1 = (const float*)d_in[5];
    const float* w_hh1 = (const float*)d_in[6];
    const float* b_ih1 = (const float*)d_in[7];
    const float* b_hh1 = (const float*)d_in[8];
    const float* w_ih2 = (const float*)d_in[9];
    const float* w_hh2 = (const float*)d_in[10];
    const float* b_ih2 = (const float*)d_in[11];
    const float* b_hh2 = (const float*)d_in[12];
    const float* w_lin = (const float*)d_in[13];
    const float* b_lin = (const float*)d_in[14];

    // Tag hygiene (stale tags from the previous replay would alias).
    zero_bufs<<<dim3(1024), dim3(256), 0, stream>>>();

    // layer 0: seq -> g_bufA
    scan_kernel<0><<<dim3(NWG), dim3(NTHR), 0, stream>>>(seq, w_ih0, w_hh0, b_ih0, b_hh0);
    // layer 1: g_bufA -> g_bufB
    scan_kernel<1><<<dim3(NWG), dim3(NTHR), 0, stream>>>(seq, w_ih1, w_hh1, b_ih1, b_hh1);
    // layer 2: g_bufB -> g_ring
    scan_kernel<2><<<dim3(NWG), dim3(NTHR), 0, stream>>>(seq, w_ih2, w_hh2, b_ih2, b_hh2);

    final_kernel<<<dim3(1), dim3(256), 0, stream>>>(w_lin, b_lin, (float*)d_out);
}